// Round 1
// 81.768 us; speedup vs baseline: 1.0334x; 1.0334x over previous
//
#include <hip/hip_runtime.h>

// PS-ROI Align: img (1,20,20,1568) f32, rois (1,8192,4) f32 -> out (1,8192,7,7,32) f32
// f[b,y,x,a] = img[(y*20+x)*1568 + b*32 + a];  out[r,p,q,a], bin = p*7+q (x<-p, y<-q).
//
// Block = (bin, 256-ROI chunk), 1024 threads, __launch_bounds__(1024,8) -> <=64 VGPR
// so 2 blocks/CU co-reside (LDS 62,592 B x2 fits 160 KB).
//   Phase A: stage bin's 20x20x32 slice into LDS with a 16B pad every 2 cells:
//            cell base byte = (c<<7) + ((c>>1)<<4). This rotates the bank set of
//            each cell by 4*((c>>1)&7), breaking the fixed-16-bank pattern of the
//            unpadded layout (ds_read_b128 was 16 banks x 16-deep before).
//   Phase B: threads 0..255 compute one coord packet per ROI.
//   Phase C: one (roi, alpha-quad-pair) item per thread: lane s of each 4-lane
//            group handles float quads s and s+4 (bytes s*16 and 64+s*16), so each
//            store instruction writes a contiguous 64 B per group.

#define CH 1568
#define IMG_W 20
#define CELLS 400
#define ROIS_PER_BLOCK 256
// padded image region: cell 399 base = 399*128 + 199*16 = 54,256; +128 -> 54,384
#define PKOFF_F 13600u           // floats (= 54,400 B, 16-aligned)
#define LDS_FLOATS (13600 + ROIS_PER_BLOCK * 8)   // 62,592 B total

// row stride in bytes: 20 cells -> 20*128 + 10*16 = 2720
#define ROW_STRIDE_B 2720u

typedef float vf4 __attribute__((ext_vector_type(4)));

__device__ __forceinline__ unsigned cell_base_b(unsigned c) {
    return (c << 7) + ((c >> 1) << 4);
}

// Distribute the two samples' 1D bilinear weights (validity mask + reference
// clamping semantics) onto 3 consecutive cells starting at base b.
__device__ __forceinline__ void axis_weights(float s0, float s1,
                                             int& b, float& W0, float& W1, float& W2)
{
    const float f0 = floorf(s0), f1 = floorf(s1);
    const float w0 = s0 - f0,    w1 = s1 - f1;
    const float v0 = (s0 >= 0.f && s0 <= 19.f) ? 1.f : 0.f;
    const float v1 = (s1 >= 0.f && s1 <= 19.f) ? 1.f : 0.f;
    const int c00 = min(max((int)f0, 0), 19);
    const int c01 = min(c00 + 1, 19);
    const int c10 = min(max((int)f1, 0), 19);   // s1 > s0 => c10 in {c00, c00+1}
    const int c11 = min(c10 + 1, 19);
    b = c00;
    W0 = v0 * (1.f - w0);
    W1 = 0.f; W2 = 0.f;
    float t = v0 * w0;
    if (c01 == b) W0 += t; else W1 += t;
    t = v1 * (1.f - w1);
    if (c10 == b) W0 += t; else W1 += t;
    t = v1 * w1;
    const int d = c11 - b;
    W0 += (d == 0) ? t : 0.f;
    W1 += (d == 1) ? t : 0.f;
    W2 += (d == 2) ? t : 0.f;
}

__global__ __launch_bounds__(1024, 8) void psroi_kernel(
    const float* __restrict__ img,
    const float* __restrict__ rois,
    float* __restrict__ out)
{
    __shared__ __align__(16) float lds[LDS_FLOATS];

    const unsigned t     = threadIdx.x;
    const unsigned bin   = blockIdx.x % 49u;
    const unsigned chunk = blockIdx.x / 49u;
    const unsigned p     = bin / 7u;          // bin_x (drives x)
    const unsigned q     = bin - p * 7u;      // bin_y (drives y)

    // ---- Phase A: stage bin slice into LDS (3200 float4, 1024 threads) ----
    {
        const float* src = img + bin * 32u;
        for (unsigned idx = t; idx < CELLS * 8u; idx += 1024u) {
            const unsigned cell = idx >> 3;       // 0..399
            const unsigned sub  = idx & 7u;       // float4 within cell
            const vf4 v = *(const vf4*)(src + (size_t)cell * CH + sub * 4u);
            // float index = byte/4 = (cell<<5) + ((cell>>1)<<2) + (sub<<2)
            *(vf4*)(&lds[(cell << 5) + ((cell >> 1) << 2) + (sub << 2)]) = v;
        }
    }

    // ---- Phase B: threads 0..255 compute one packet per ROI ----
    if (t < ROIS_PER_BLOCK) {
        const unsigned r = chunk * ROIS_PER_BLOCK + t;
        const vf4 roi = ((const vf4*)rois)[r];
        const float step_x = roi.z * (1.0f / 7.0f);
        const float step_y = roi.w * (1.0f / 7.0f);
        const float s = 19.0f / 20.0f;
        const float sx0 = (roi.x + (float)p * step_x) * s;
        const float sx1 = (roi.x + (float)(p + 1) * step_x) * s;
        const float sy0 = (roi.y + (float)q * step_y) * s;
        const float sy1 = (roi.y + (float)(q + 1) * step_y) * s;

        int bx, by;
        float WX0, WX1, WX2, WY0, WY1, WY2;
        axis_weights(sx0, sx1, bx, WX0, WX1, WX2);
        axis_weights(sy0, sy1, by, WY0, WY1, WY2);

        vf4 p0, p1;
        p0.x = __int_as_float(bx);
        p0.y = __int_as_float(by);
        p0.z = WX0; p0.w = WX1;
        p1.x = WX2;
        p1.y = WY0 * 0.25f; p1.z = WY1 * 0.25f; p1.w = WY2 * 0.25f;  // fold mean
        *(vf4*)(&lds[PKOFF_F + t * 8u])     = p0;
        *(vf4*)(&lds[PKOFF_F + t * 8u + 4]) = p1;
    }

    __syncthreads();

    // ---- Phase C: one (roi, quad-pair) work item per thread ----
    const unsigned rl = t >> 2;              // roi_local 0..255
    const unsigned s  = t & 3u;              // quad selector: quads s and s+4

    const float* pkp = &lds[PKOFF_F + rl * 8u];
    const vf4 p0 = *(const vf4*)pkp;
    const vf4 p1 = *(const vf4*)(pkp + 4);
    const int bx = __float_as_int(p0.x);
    const int by = __float_as_int(p0.y);
    const float WX[3] = { p0.z, p0.w, p1.x };
    const float WY[3] = { p1.y, p1.z, p1.w };
    const unsigned sb = s << 4;              // byte offset of quad s

    const unsigned col0 = (unsigned)bx;
    const unsigned col1 = (unsigned)min(bx + 1, 19);
    const unsigned col2 = (unsigned)min(bx + 2, 19);
    const unsigned row0 = (unsigned)by;
    const unsigned row1 = (unsigned)min(by + 1, 19);
    const unsigned row2 = (unsigned)min(by + 2, 19);
    const unsigned colb[3] = { cell_base_b(col0) + sb,
                               cell_base_b(col1) + sb,
                               cell_base_b(col2) + sb };
    const unsigned rowb[3] = { row0 * ROW_STRIDE_B,
                               row1 * ROW_STRIDE_B,
                               row2 * ROW_STRIDE_B };

    const char* ldsb = (const char*)lds;
    vf4 acc0 = { 0.f, 0.f, 0.f, 0.f };
    vf4 acc1 = { 0.f, 0.f, 0.f, 0.f };
#pragma unroll
    for (int i = 0; i < 3; ++i) {
#pragma unroll
        for (int j = 0; j < 3; ++j) {
            const char* cp = ldsb + (rowb[i] + colb[j]);
            const vf4 v0 = *(const vf4*)cp;           // alphas 4s..4s+3
            const vf4 v1 = *(const vf4*)(cp + 64);    // alphas 16+4s..16+4s+3
            const float wgt = WY[i] * WX[j];
            acc0 += wgt * v0;
            acc1 += wgt * v1;
        }
    }

    // out: acc0 -> floats s*4..s*4+3, acc1 -> floats 16+s*4..; each 4-lane group's
    // store instruction covers a contiguous 64 B segment.
    const size_t ob = ((size_t)chunk * ROIS_PER_BLOCK + rl) * (49u * 32u)
                    + bin * 32u + s * 4u;
    __builtin_nontemporal_store(acc0, (vf4*)(out + ob));
    __builtin_nontemporal_store(acc1, (vf4*)(out + ob + 16));
}

extern "C" void kernel_launch(void* const* d_in, const int* in_sizes, int n_in,
                              void* d_out, int out_size, void* d_ws, size_t ws_size,
                              hipStream_t stream) {
    const float* img  = (const float*)d_in[0];
    const float* rois = (const float*)d_in[1];
    float* out = (float*)d_out;
    // grid = 49 bins * 32 chunks of 256 ROIs = 1568 blocks of 1024 threads
    hipLaunchKernelGGL(psroi_kernel, dim3(1568), dim3(1024), 0, stream, img, rois, out);
}

// Round 2
// 80.349 us; speedup vs baseline: 1.0516x; 1.0177x over previous
//
#include <hip/hip_runtime.h>

// PS-ROI Align: img (1,20,20,1568) f32, rois (1,8192,4) f32 -> out (1,8192,7,7,32) f32
// f[b,y,x,a] = img[(y*20+x)*1568 + b*32 + a];  out[r,p,q,a], bin = p*7+q (x<-p, y<-q).
//
// Block = (bin, 256-ROI chunk), 1024 threads, __launch_bounds__(1024,8) -> <=64 VGPR,
// 2 blocks/CU (LDS 59,392 B x2 = 118.8 KB < 160 KB).
//   Phase A: stage bin's 20x20x32 slice (51.2 KB) into LDS, UNPADDED: cell lines are
//            128 B contiguous and 128 B aligned.
//   Phase B: threads 0..255 compute one coord packet per ROI.
//   Phase C: 8 lanes per ROI (lane s owns alpha quad s), 2 ROIs per thread (rl, rl+128).
//            Each group's ds_read_b128 covers a full 128 B cell line = all 32 banks
//            exactly once -> 8 groups/wave give EXACTLY 8-deep uniform bank load
//            (the minimum for 1 KB) regardless of data-dependent cell addresses.
//            Zero bank conflicts by construction. Stores: one vf4 per ROI-pass;
//            each 8-lane group writes a contiguous 128 B output segment.

#define CH 1568
#define IMG_W 20
#define CELLS 400
#define ROIS_PER_BLOCK 256
#define IMG_F (CELLS * 32)              // 12800 floats = 51.2 KB
#define PKOFF IMG_F                     // packet area: 256 rois * 8 floats = 8 KB
#define LDS_FLOATS (IMG_F + ROIS_PER_BLOCK * 8)   // 59,392 B

typedef float vf4 __attribute__((ext_vector_type(4)));

// Distribute the two samples' 1D bilinear weights (validity mask + reference
// clamping semantics) onto 3 consecutive cells starting at base b.
__device__ __forceinline__ void axis_weights(float s0, float s1,
                                             int& b, float& W0, float& W1, float& W2)
{
    const float f0 = floorf(s0), f1 = floorf(s1);
    const float w0 = s0 - f0,    w1 = s1 - f1;
    const float v0 = (s0 >= 0.f && s0 <= 19.f) ? 1.f : 0.f;
    const float v1 = (s1 >= 0.f && s1 <= 19.f) ? 1.f : 0.f;
    const int c00 = min(max((int)f0, 0), 19);
    const int c01 = min(c00 + 1, 19);
    const int c10 = min(max((int)f1, 0), 19);   // s1 > s0 => c10 in {c00, c00+1}
    const int c11 = min(c10 + 1, 19);
    b = c00;
    W0 = v0 * (1.f - w0);
    W1 = 0.f; W2 = 0.f;
    float t = v0 * w0;
    if (c01 == b) W0 += t; else W1 += t;
    t = v1 * (1.f - w1);
    if (c10 == b) W0 += t; else W1 += t;
    t = v1 * w1;
    const int d = c11 - b;
    W0 += (d == 0) ? t : 0.f;
    W1 += (d == 1) ? t : 0.f;
    W2 += (d == 2) ? t : 0.f;
}

__global__ __launch_bounds__(1024, 8) void psroi_kernel(
    const float* __restrict__ img,
    const float* __restrict__ rois,
    float* __restrict__ out)
{
    __shared__ __align__(16) float lds[LDS_FLOATS];

    const unsigned t     = threadIdx.x;
    const unsigned bin   = blockIdx.x % 49u;
    const unsigned chunk = blockIdx.x / 49u;
    const unsigned p     = bin / 7u;          // bin_x (drives x)
    const unsigned q     = bin - p * 7u;      // bin_y (drives y)

    // ---- Phase A: stage bin slice into LDS (3200 float4, 1024 threads) ----
    // Wave of 64 lanes writes 1 KB contiguous -> uniform 8-deep banks, conflict-free.
    {
        const float* src = img + bin * 32u;
        for (unsigned idx = t; idx < CELLS * 8u; idx += 1024u) {
            const unsigned cell = idx >> 3;       // 0..399
            const unsigned sub  = idx & 7u;       // float4 within cell
            const vf4 v = *(const vf4*)(src + (size_t)cell * CH + sub * 4u);
            *(vf4*)(&lds[cell * 32u + sub * 4u]) = v;
        }
    }

    // ---- Phase B: threads 0..255 compute one packet per ROI ----
    if (t < ROIS_PER_BLOCK) {
        const unsigned r = chunk * ROIS_PER_BLOCK + t;
        const vf4 roi = ((const vf4*)rois)[r];
        const float step_x = roi.z * (1.0f / 7.0f);
        const float step_y = roi.w * (1.0f / 7.0f);
        const float s = 19.0f / 20.0f;
        const float sx0 = (roi.x + (float)p * step_x) * s;
        const float sx1 = (roi.x + (float)(p + 1) * step_x) * s;
        const float sy0 = (roi.y + (float)q * step_y) * s;
        const float sy1 = (roi.y + (float)(q + 1) * step_y) * s;

        int bx, by;
        float WX0, WX1, WX2, WY0, WY1, WY2;
        axis_weights(sx0, sx1, bx, WX0, WX1, WX2);
        axis_weights(sy0, sy1, by, WY0, WY1, WY2);

        vf4 p0, p1;
        p0.x = __int_as_float(bx);
        p0.y = __int_as_float(by);
        p0.z = WX0; p0.w = WX1;
        p1.x = WX2;
        p1.y = WY0 * 0.25f; p1.z = WY1 * 0.25f; p1.w = WY2 * 0.25f;  // fold mean
        *(vf4*)(&lds[PKOFF + t * 8u])     = p0;
        *(vf4*)(&lds[PKOFF + t * 8u + 4]) = p1;
    }

    __syncthreads();

    // ---- Phase C: 8 lanes per ROI, 2 ROIs per thread ----
    const unsigned g  = t >> 3;              // group 0..127
    const unsigned s  = t & 7u;              // alpha quad selector 0..7
    const unsigned sb = s << 4;              // byte offset within 128 B cell line
    const char* ldsb = (const char*)lds;

#pragma unroll
    for (int pass = 0; pass < 2; ++pass) {
        const unsigned rl = g + (unsigned)pass * 128u;

        const float* pkp = &lds[PKOFF + rl * 8u];   // 8-lane broadcast read
        const vf4 p0 = *(const vf4*)pkp;
        const vf4 p1 = *(const vf4*)(pkp + 4);
        const int bx = __float_as_int(p0.x);
        const int by = __float_as_int(p0.y);
        const float WX[3] = { p0.z, p0.w, p1.x };
        const float WY[3] = { p1.y, p1.z, p1.w };

        const unsigned colb[3] = { (unsigned)bx * 128u + sb,
                                   (unsigned)min(bx + 1, 19) * 128u + sb,
                                   (unsigned)min(bx + 2, 19) * 128u + sb };
        const unsigned rowb[3] = { (unsigned)by * 2560u,
                                   (unsigned)min(by + 1, 19) * 2560u,
                                   (unsigned)min(by + 2, 19) * 2560u };

        vf4 acc = { 0.f, 0.f, 0.f, 0.f };
#pragma unroll
        for (int i = 0; i < 3; ++i) {
#pragma unroll
            for (int j = 0; j < 3; ++j) {
                const vf4 v = *(const vf4*)(ldsb + (rowb[i] + colb[j]));
                acc += (WY[i] * WX[j]) * v;
            }
        }

        // 8-lane group writes contiguous 128 B: floats [bin*32 .. bin*32+31]
        const size_t ob = ((size_t)chunk * ROIS_PER_BLOCK + rl) * (49u * 32u)
                        + bin * 32u + s * 4u;
        __builtin_nontemporal_store(acc, (vf4*)(out + ob));
    }
}

extern "C" void kernel_launch(void* const* d_in, const int* in_sizes, int n_in,
                              void* d_out, int out_size, void* d_ws, size_t ws_size,
                              hipStream_t stream) {
    const float* img  = (const float*)d_in[0];
    const float* rois = (const float*)d_in[1];
    float* out = (float*)d_out;
    // grid = 49 bins * 32 chunks of 256 ROIs = 1568 blocks of 1024 threads
    hipLaunchKernelGGL(psroi_kernel, dim3(1568), dim3(1024), 0, stream, img, rois, out);
}